// Round 4
// baseline (309.724 us; speedup 1.0000x reference)
//
#include <hip/hip_runtime.h>

// WeightedBCELoss: out[b][s] = labels==0 ? -log(1-pred) : -weight[b]*log(pred)
// BATCH=4096, SENT=8192, fp32 (labels int32). 402 MB/pass.
//
// R4: exact R0 (fastest: 102.5 us/dispatch, 2.6 TB/s HBM) with ONE change:
// nontemporal output store. Theory: FETCH_SIZE is pinned at exactly 128 MiB
// = output size because the write stream ALLOCATES in the 256 MiB L3 and
// evicts half of the exactly-L3-sized input set each pass (write-allocate
// steady state). nt store -> writes bypass L3 -> inputs fully resident ->
// FETCH drops toward 0. Unconfounded A/B vs R0 (R2's nt test was confounded
// with a layout change that itself regressed).
// Evidence against other levers: MLP abundant (96 KB in flight/CU vs ~9 KB
// needed), VALUBusy 14%, and depth-4/depth-16 batching both regressed.

#define WBCE_BATCH 4096
#define WBCE_SENT  8192
// float4 groups per row = SENT/4 = 2048 = 1<<11
#define LOG2_VEC_PER_ROW 11

typedef float f32x4 __attribute__((ext_vector_type(4)));

__global__ __launch_bounds__(256) void WeightedBCELoss_70128226009669_kernel(
    const float4* __restrict__ pred4,
    const int4*  __restrict__ lab4,
    const float* __restrict__ weight,
    float4* __restrict__ out4)
{
    const int i = blockIdx.x * 256 + threadIdx.x;
    // Every wave covers indices within one row (2048 vec/row, multiple of 64),
    // so this load is wave-uniform -> scalar path.
    const int row = i >> LOG2_VEC_PER_ROW;
    const float w = weight[row];

    const float4 p = pred4[i];
    const int4  l = lab4[i];

    // Select the log argument first so we pay only ONE log per element.
    const float x0 = (l.x == 0) ? (1.0f - p.x) : p.x;
    const float x1 = (l.y == 0) ? (1.0f - p.y) : p.y;
    const float x2 = (l.z == 0) ? (1.0f - p.z) : p.z;
    const float x3 = (l.w == 0) ? (1.0f - p.w) : p.w;

    const float s0 = (l.x == 0) ? 1.0f : w;
    const float s1 = (l.y == 0) ? 1.0f : w;
    const float s2 = (l.z == 0) ? 1.0f : w;
    const float s3 = (l.w == 0) ? 1.0f : w;

    f32x4 o;
    o.x = -s0 * __logf(x0);
    o.y = -s1 * __logf(x1);
    o.z = -s2 * __logf(x2);
    o.w = -s3 * __logf(x3);

    // THE one change vs R0: streaming store (output is never re-read).
    __builtin_nontemporal_store(o, (f32x4*)&out4[i]);
}

extern "C" void kernel_launch(void* const* d_in, const int* in_sizes, int n_in,
                              void* d_out, int out_size, void* d_ws, size_t ws_size,
                              hipStream_t stream) {
    const float4* pred4  = (const float4*)d_in[0];
    const int4*   lab4   = (const int4*)d_in[1];
    const float*  weight = (const float*)d_in[2];
    float4* out4 = (float4*)d_out;

    const int n_vec = (WBCE_BATCH * WBCE_SENT) / 4;  // 8,388,608
    const int block = 256;
    const int grid = n_vec / block;                  // 32,768 — exact, no tail

    WeightedBCELoss_70128226009669_kernel<<<grid, block, 0, stream>>>(
        pred4, lab4, weight, out4);
}

// Round 5
// 300.047 us; speedup vs baseline: 1.0323x; 1.0323x over previous
//
#include <hip/hip_runtime.h>

// WeightedBCELoss: out[b][s] = labels==0 ? -log(1-pred) : -weight[b]*log(pred)
// BATCH=4096, SENT=8192, fp32 (labels int32). 402 MB/pass.
//
// R5: exact R0 structure (fastest measured: 102.5 us/dispatch) with ONE
// change: block size 256 -> 64 (1 wave per block).
// Theory: OccupancyPercent is stuck at ~70% despite VGPR=12/no-LDS. One-shot
// 256-thread blocks need 4 wave slots on one CU to launch; slots free at
// latency-jittered times, so ~30% sit idle waiting for block-granularity
// backfill. 1-wave blocks recycle every slot immediately -> more waves
// resident -> more loads in flight -> higher memory throughput.
// Dead theories (measured): MLP depth (R2/R3 regressed monotonically with
// depth), nt stores (R4: -15%, FETCH unchanged), grid-stride layout (R2).
// Decision rule: occupancy up + dur flat => 3-stream mix at ~3.9 TB/s is
// the structural wall -> ROOFLINE next round.

#define WBCE_BATCH 4096
#define WBCE_SENT  8192
// float4 groups per row = SENT/4 = 2048 = 1<<11
#define LOG2_VEC_PER_ROW 11

#define THREADS 64   // 1 wave per block: per-wave slot recycling, no block tail

__global__ __launch_bounds__(THREADS) void WeightedBCELoss_70128226009669_kernel(
    const float4* __restrict__ pred4,
    const int4*  __restrict__ lab4,
    const float* __restrict__ weight,
    float4* __restrict__ out4)
{
    const int i = blockIdx.x * THREADS + threadIdx.x;
    // 2048 float4/row is a multiple of 64 -> the whole wave shares one row,
    // so this resolves to a wave-uniform scalar load.
    const int row = i >> LOG2_VEC_PER_ROW;
    const float w = weight[row];

    const float4 p = pred4[i];
    const int4  l = lab4[i];

    // Select the log argument first so we pay only ONE log per element.
    const float x0 = (l.x == 0) ? (1.0f - p.x) : p.x;
    const float x1 = (l.y == 0) ? (1.0f - p.y) : p.y;
    const float x2 = (l.z == 0) ? (1.0f - p.z) : p.z;
    const float x3 = (l.w == 0) ? (1.0f - p.w) : p.w;

    const float s0 = (l.x == 0) ? 1.0f : w;
    const float s1 = (l.y == 0) ? 1.0f : w;
    const float s2 = (l.z == 0) ? 1.0f : w;
    const float s3 = (l.w == 0) ? 1.0f : w;

    float4 o;
    o.x = -s0 * __logf(x0);
    o.y = -s1 * __logf(x1);
    o.z = -s2 * __logf(x2);
    o.w = -s3 * __logf(x3);

    out4[i] = o;
}

extern "C" void kernel_launch(void* const* d_in, const int* in_sizes, int n_in,
                              void* d_out, int out_size, void* d_ws, size_t ws_size,
                              hipStream_t stream) {
    const float4* pred4  = (const float4*)d_in[0];
    const int4*   lab4   = (const int4*)d_in[1];
    const float*  weight = (const float*)d_in[2];
    float4* out4 = (float4*)d_out;

    const int n_vec = (WBCE_BATCH * WBCE_SENT) / 4;  // 8,388,608
    const int grid = n_vec / THREADS;                // 131,072 — exact, no tail

    WeightedBCELoss_70128226009669_kernel<<<grid, THREADS, 0, stream>>>(
        pred4, lab4, weight, out4);
}